// Round 1
// baseline (94.082 us; speedup 1.0000x reference)
//
#include <hip/hip_runtime.h>

#define SMOOTH 1.0f

// ---------------------------------------------------------------------------
// Kernel 1: grid-stride float4 pass over pred/target, masked triple reduction.
// Writes per-block partials (SoA: [I | A | B]) into ws for kernel 2.
// ---------------------------------------------------------------------------
__global__ __launch_bounds__(256) void dice_partial(
    const float* __restrict__ pred,
    const float* __restrict__ target,
    float* __restrict__ partials,   // [3 * gridDim.x], SoA
    int n)                          // total elements
{
    const int n4 = n >> 2;          // number of float4 chunks
    const int tid = blockIdx.x * blockDim.x + threadIdx.x;
    const int stride = gridDim.x * blockDim.x;

    const float4* __restrict__ p4 = reinterpret_cast<const float4*>(pred);
    const float4* __restrict__ t4 = reinterpret_cast<const float4*>(target);

    float si = 0.0f, sa = 0.0f, sb = 0.0f;

    for (int i = tid; i < n4; i += stride) {
        float4 p = p4[i];
        float4 t = t4[i];

        float m;
        m = (t.x > -1.0f) ? 1.0f : 0.0f;
        si = fmaf(p.x * t.x, m, si); sa = fmaf(p.x * p.x, m, sa); sb = fmaf(t.x * t.x, m, sb);
        m = (t.y > -1.0f) ? 1.0f : 0.0f;
        si = fmaf(p.y * t.y, m, si); sa = fmaf(p.y * p.y, m, sa); sb = fmaf(t.y * t.y, m, sb);
        m = (t.z > -1.0f) ? 1.0f : 0.0f;
        si = fmaf(p.z * t.z, m, si); sa = fmaf(p.z * p.z, m, sa); sb = fmaf(t.z * t.z, m, sb);
        m = (t.w > -1.0f) ? 1.0f : 0.0f;
        si = fmaf(p.w * t.w, m, si); sa = fmaf(p.w * p.w, m, sa); sb = fmaf(t.w * t.w, m, sb);
    }

    // Scalar tail (n not divisible by 4) — handled once by thread 0 of block 0.
    if (tid == 0) {
        for (int i = n4 << 2; i < n; ++i) {
            float p = pred[i], t = target[i];
            float m = (t > -1.0f) ? 1.0f : 0.0f;
            si = fmaf(p * t, m, si); sa = fmaf(p * p, m, sa); sb = fmaf(t * t, m, sb);
        }
    }

    // Wave (64-lane) butterfly reduction.
    #pragma unroll
    for (int off = 32; off > 0; off >>= 1) {
        si += __shfl_down(si, off);
        sa += __shfl_down(sa, off);
        sb += __shfl_down(sb, off);
    }

    __shared__ float lds[3][4];     // 4 waves per 256-thread block
    const int wave = threadIdx.x >> 6;
    const int lane = threadIdx.x & 63;
    if (lane == 0) {
        lds[0][wave] = si; lds[1][wave] = sa; lds[2][wave] = sb;
    }
    __syncthreads();

    if (threadIdx.x == 0) {
        float ti = 0.0f, ta = 0.0f, tb = 0.0f;
        #pragma unroll
        for (int w = 0; w < 4; ++w) {
            ti += lds[0][w]; ta += lds[1][w]; tb += lds[2][w];
        }
        const int G = gridDim.x;
        partials[blockIdx.x]         = ti;
        partials[G + blockIdx.x]     = ta;
        partials[2 * G + blockIdx.x] = tb;
    }
}

// ---------------------------------------------------------------------------
// Kernel 2: single block reduces the per-block partials, writes the scalar.
// ---------------------------------------------------------------------------
__global__ __launch_bounds__(256) void dice_final(
    const float* __restrict__ partials,
    int nblocks,
    float* __restrict__ out)
{
    float si = 0.0f, sa = 0.0f, sb = 0.0f;
    for (int i = threadIdx.x; i < nblocks; i += blockDim.x) {
        si += partials[i];
        sa += partials[nblocks + i];
        sb += partials[2 * nblocks + i];
    }

    #pragma unroll
    for (int off = 32; off > 0; off >>= 1) {
        si += __shfl_down(si, off);
        sa += __shfl_down(sa, off);
        sb += __shfl_down(sb, off);
    }

    __shared__ float lds[3][4];
    const int wave = threadIdx.x >> 6;
    const int lane = threadIdx.x & 63;
    if (lane == 0) {
        lds[0][wave] = si; lds[1][wave] = sa; lds[2][wave] = sb;
    }
    __syncthreads();

    if (threadIdx.x == 0) {
        float ti = 0.0f, ta = 0.0f, tb = 0.0f;
        #pragma unroll
        for (int w = 0; w < 4; ++w) {
            ti += lds[0][w]; ta += lds[1][w]; tb += lds[2][w];
        }
        out[0] = 1.0f - (2.0f * ti + SMOOTH) / (ta + tb + SMOOTH);
    }
}

extern "C" void kernel_launch(void* const* d_in, const int* in_sizes, int n_in,
                              void* d_out, int out_size, void* d_ws, size_t ws_size,
                              hipStream_t stream) {
    const float* pred   = (const float*)d_in[0];
    const float* target = (const float*)d_in[1];
    float* out = (float*)d_out;
    float* partials = (float*)d_ws;   // needs 3 * GRID * 4 bytes

    const int n = in_sizes[0];
    const int GRID = 2048;            // 256 CUs * 8 blocks — memory-bound sweet spot
    const int BLOCK = 256;

    dice_partial<<<GRID, BLOCK, 0, stream>>>(pred, target, partials, n);
    dice_final<<<1, BLOCK, 0, stream>>>(partials, GRID, out);
}